// Round 1
// baseline (55.982 us; speedup 1.0000x reference)
//
#include <hip/hip_runtime.h>
#include <math.h>

// Strict IEEE f32, no mul+add fusion: edge-function sign decisions must match
// the numpy reference bit-for-bit at triangle boundaries (a flipped winner is a
// depth error of up to 100 vs threshold 2.0).
#pragma clang fp contract(off)

#define RES        512
#define MAXF       128
#define MAX_DEPTH  100.0f
#define AMBIENT    0.3f
#define LIGHT_STREN 0.8f
#define EPSF       1e-8f

__global__ __launch_bounds__(256) void mesh_render_kernel(
    const float* __restrict__ verts,     // (N,3)
    const int*   __restrict__ faces,     // (M,3)
    const float* __restrict__ normals,   // (M,3,3)
    const float* __restrict__ uvs,       // (M,3,2)
    const float* __restrict__ tex,       // (TH,TW,3)
    const float* __restrict__ Ks,        // (3,3)
    const float* __restrict__ RTs,       // (3,4)
    const float* __restrict__ view_dir,  // (3,)
    const float* __restrict__ light_dir, // (3,)
    float* __restrict__ out,             // [depth | rgb | mask]
    int M, int TEXW, int TEXH)
{
    // Per face: e0{dx,dy,ax,ay} e1{...} e2{...} z0 z1 z2 pad  -> 16 floats
    __shared__ float fd[MAXF][16];
    const int tid = threadIdx.x;

    if (tid < M && tid < MAXF) {
        const float r00 = RTs[0], r01 = RTs[1], r02 = RTs[2],  t0 = RTs[3];
        const float r10 = RTs[4], r11 = RTs[5], r12 = RTs[6],  t1 = RTs[7];
        const float r20 = RTs[8], r21 = RTs[9], r22 = RTs[10], t2 = RTs[11];
        const float k00 = Ks[0], k02 = Ks[2], k11 = Ks[4], k12 = Ks[5];
        float X[3], Y[3], Z[3];
        #pragma unroll
        for (int k = 0; k < 3; ++k) {
            int vi = faces[tid * 3 + k];
            float vx = verts[vi * 3 + 0];
            float vy = verts[vi * 3 + 1];
            float vz = verts[vi * 3 + 2];
            // cam = RT[:,:3] @ v + RT[:,3]   (left-to-right sum like einsum)
            float cx = ((r00 * vx + r01 * vy) + r02 * vz) + t0;
            float cy = ((r10 * vx + r11 * vy) + r12 * vz) + t1;
            float cz = ((r20 * vx + r21 * vy) + r22 * vz) + t2;
            X[k] = k00 * cx + k02;
            Y[k] = k11 * cy + k12;
            Z[k] = cz;
        }
        float* d = fd[tid];
        // w0 = edge(v1, v2, p); w1 = edge(v2, v0, p); w2 = edge(v0, v1, p)
        d[0]  = X[2] - X[1]; d[1]  = Y[2] - Y[1]; d[2]  = X[1]; d[3]  = Y[1];
        d[4]  = X[0] - X[2]; d[5]  = Y[0] - Y[2]; d[6]  = X[2]; d[7]  = Y[2];
        d[8]  = X[1] - X[0]; d[9]  = Y[1] - Y[0]; d[10] = X[0]; d[11] = Y[0];
        d[12] = Z[0]; d[13] = Z[1]; d[14] = Z[2]; d[15] = 0.0f;
    }
    __syncthreads();

    const int p = blockIdx.x * blockDim.x + tid;
    if (p >= RES * RES) return;
    const float px = (float)(p % RES) + 0.5f;  // column
    const float py = (float)(p / RES) + 0.5f;  // row

    // ---- depth pass: min-z with first-occurrence argmin tie-break ----
    float best = MAX_DEPTH;
    int   win  = -1;
    for (int f = 0; f < M; ++f) {
        const float4 q0 = *reinterpret_cast<const float4*>(&fd[f][0]);
        const float4 q1 = *reinterpret_cast<const float4*>(&fd[f][4]);
        const float4 q2 = *reinterpret_cast<const float4*>(&fd[f][8]);
        const float4 q3 = *reinterpret_cast<const float4*>(&fd[f][12]);
        float w0 = q0.x * (py - q0.w) - q0.y * (px - q0.z);
        float w1 = q1.x * (py - q1.w) - q1.y * (px - q1.z);
        float w2 = q2.x * (py - q2.w) - q2.y * (px - q2.z);
        float area = (w0 + w1) + w2;
        bool nz = fabsf(area) > EPSF;
        bool inside = (((w0 >= 0.0f) && (w1 >= 0.0f) && (w2 >= 0.0f)) ||
                       ((w0 <= 0.0f) && (w1 <= 0.0f) && (w2 <= 0.0f))) && nz;
        float inva = 1.0f / (nz ? area : 1.0f);
        float zpix = ((w0 * q3.x + w1 * q3.y) + w2 * q3.z) * inva;
        float zc = (inside && (zpix > 0.0f)) ? zpix : MAX_DEPTH;
        if (zc < best) { best = zc; win = f; }   // strict < == argmin first idx
    }

    float r = 0.0f, g = 0.0f, b = 0.0f, mk = 0.0f, depth = MAX_DEPTH;
    if (win >= 0) {
        mk = 1.0f;
        depth = best;
        const float* d = fd[win];
        // recompute barycentrics for winner (same arithmetic as the loop)
        float u0 = d[0] * (py - d[3])  - d[1] * (px - d[2]);
        float u1 = d[4] * (py - d[7])  - d[5] * (px - d[6]);
        float u2 = d[8] * (py - d[11]) - d[9] * (px - d[10]);
        float ar = (u0 + u1) + u2;
        float inv2 = 1.0f / ((fabsf(ar) > EPSF) ? ar : 1.0f);
        float b0 = u0 * inv2, b1 = u1 * inv2, b2 = u2 * inv2;

        const float* nw = normals + win * 9;
        float nx = (b0 * nw[0] + b1 * nw[3]) + b2 * nw[6];
        float ny = (b0 * nw[1] + b1 * nw[4]) + b2 * nw[7];
        float nzv = (b0 * nw[2] + b1 * nw[5]) + b2 * nw[8];
        float nl = sqrtf((nx * nx + ny * ny) + nzv * nzv) + 1e-8f;
        nx /= nl; ny /= nl; nzv /= nl;

        const float* uvp = uvs + win * 6;
        float uvx = (b0 * uvp[0] + b1 * uvp[2]) + b2 * uvp[4];
        float uvy = (b0 * uvp[1] + b1 * uvp[3]) + b2 * uvp[5];
        float uu = fminf(fmaxf(uvx, 0.0f), 1.0f) * (float)(TEXW - 1);
        float vv = fminf(fmaxf(uvy, 0.0f), 1.0f) * (float)(TEXH - 1);
        int x0 = (int)floorf(uu), y0 = (int)floorf(vv);
        int x1 = min(x0 + 1, TEXW - 1), y1 = min(y0 + 1, TEXH - 1);
        float fx = uu - (float)x0, fy = vv - (float)y0;
        const float* t00 = tex + (y0 * TEXW + x0) * 3;
        const float* t01 = tex + (y0 * TEXW + x1) * 3;
        const float* t10 = tex + (y1 * TEXW + x0) * 3;
        const float* t11 = tex + (y1 * TEXW + x1) * 3;
        float gx = 1.0f - fx, gy = 1.0f - fy;
        // col = ((t00*(1-fx))*(1-fy) + (t01*fx)*(1-fy)) + (t10*(1-fx))*fy + (t11*fx)*fy
        float cr = (((t00[0] * gx) * gy + (t01[0] * fx) * gy) + (t10[0] * gx) * fy) + (t11[0] * fx) * fy;
        float cg = (((t00[1] * gx) * gy + (t01[1] * fx) * gy) + (t10[1] * gx) * fy) + (t11[1] * fx) * fy;
        float cb = (((t00[2] * gx) * gy + (t01[2] * fx) * gy) + (t10[2] * gx) * fy) + (t11[2] * fx) * fy;

        float lx = light_dir[0], ly = light_dir[1], lz = light_dir[2];
        float ll = sqrtf((lx * lx + ly * ly) + lz * lz) + 1e-8f;
        lx /= ll; ly /= ll; lz /= ll;
        float vx = view_dir[0], vy = view_dir[1], vz = view_dir[2];
        float vl = sqrtf((vx * vx + vy * vy) + vz * vz) + 1e-8f;
        vx /= vl; vy /= vl; vz /= vl;
        float hx = lx + vx, hy = ly + vy, hz = lz + vz;
        float hl = sqrtf((hx * hx + hy * hy) + hz * hz) + 1e-8f;
        hx /= hl; hy /= hl; hz /= hl;

        float diff = fmaxf((nx * lx + ny * ly) + nzv * lz, 0.0f);
        float sdot = fmaxf((nx * hx + ny * hy) + nzv * hz, 0.0f);
        float spec = LIGHT_STREN * powf(sdot, 16.0f);
        float scale = AMBIENT + LIGHT_STREN * diff;
        r = cr * scale + spec;
        g = cg * scale + spec;
        b = cb * scale + spec;
    }

    out[p] = depth;
    float* rgb = out + RES * RES;
    rgb[3 * p + 0] = r;
    rgb[3 * p + 1] = g;
    rgb[3 * p + 2] = b;
    out[RES * RES * 4 + p] = mk;
}

extern "C" void kernel_launch(void* const* d_in, const int* in_sizes, int n_in,
                              void* d_out, int out_size, void* d_ws, size_t ws_size,
                              hipStream_t stream) {
    const float* verts     = (const float*)d_in[0];
    const int*   faces     = (const int*)  d_in[1];
    const float* normals   = (const float*)d_in[2];
    const float* uvs       = (const float*)d_in[3];
    const float* tex       = (const float*)d_in[4];
    const float* Ks        = (const float*)d_in[5];
    const float* RTs       = (const float*)d_in[6];
    const float* view_dir  = (const float*)d_in[7];
    const float* light_dir = (const float*)d_in[8];

    const int M = in_sizes[1] / 3;                       // faces
    const int texels = in_sizes[4] / 3;                  // TEX*TEX
    const int TEXW = (int)(sqrt((double)texels) + 0.5);
    const int TEXH = TEXW;

    const int threads = 256;
    const int blocks = (RES * RES + threads - 1) / threads;
    mesh_render_kernel<<<blocks, threads, 0, stream>>>(
        verts, faces, normals, uvs, tex, Ks, RTs, view_dir, light_dir,
        (float*)d_out, M, TEXW, TEXH);
}

// Round 2
// 18.543 us; speedup vs baseline: 3.0191x; 3.0191x over previous
//
#include <hip/hip_runtime.h>
#include <math.h>

// Strict IEEE f32, no mul+add fusion in the decision path: edge-function sign
// decisions must match the numpy reference bit-for-bit (a flipped hit/miss at
// a silhouette is a depth error of ~98 vs threshold 2.0).
#pragma clang fp contract(off)

#define RES         512
#define TILE        16
#define TILESX      (RES / TILE)
#define MAXF        128
#define MAX_DEPTH   100.0f
#define AMBIENT     0.3f
#define LIGHT_STREN 0.8f
#define EPSF        1e-8f
#define MARG        1.0f   // conservative SAT margin, >> fp rounding at |w|~3e5

__global__ __launch_bounds__(256) void mesh_render_tiled(
    const float* __restrict__ verts,     // (N,3)
    const int*   __restrict__ faces,     // (M,3)
    const float* __restrict__ normals,   // (M,3,3)
    const float* __restrict__ uvs,       // (M,3,2)
    const float* __restrict__ tex,       // (TH,TW,3)
    const float* __restrict__ Ks,        // (3,3)
    const float* __restrict__ RTs,       // (3,4)
    const float* __restrict__ view_dir,  // (3,)
    const float* __restrict__ light_dir, // (3,)
    float* __restrict__ out,             // [depth | rgb | mask]
    int M, int TEXW, int TEXH)
{
    // Compacted per-face data for faces overlapping this tile:
    // e0{dx,dy,ax,ay} e1{...} e2{...} z0 z1 z2 pad -> 16 floats
    __shared__ float cfd[MAXF][16];
    __shared__ int   cid[MAXF];
    __shared__ unsigned long long smask[2];
    __shared__ float slit[6];            // ld(3), h(3) normalized

    const int tid = threadIdx.x;
    const int tx  = blockIdx.x % TILESX;
    const int ty  = blockIdx.x / TILESX;
    const float PX0 = (float)(tx * TILE) + 0.5f;   // first pixel-center x
    const float PY0 = (float)(ty * TILE) + 0.5f;

    // ---------- phase 0+1: transform one face/thread, tile-cull (SAT) ----------
    bool flag = false;
    float e0dx=0,e0dy=0,e0ax=0,e0ay=0, e1dx=0,e1dy=0,e1ax=0,e1ay=0;
    float e2dx=0,e2dy=0,e2ax=0,e2ay=0, Z0=0,Z1=0,Z2=0;
    unsigned long long mymask = 0;

    if (tid < MAXF) {
        if (tid < M) {
            const float r00 = RTs[0], r01 = RTs[1], r02 = RTs[2],  t0 = RTs[3];
            const float r10 = RTs[4], r11 = RTs[5], r12 = RTs[6],  t1 = RTs[7];
            const float r20 = RTs[8], r21 = RTs[9], r22 = RTs[10], t2 = RTs[11];
            const float k00 = Ks[0], k02 = Ks[2], k11 = Ks[4], k12 = Ks[5];
            float X[3], Y[3], Z[3];
            #pragma unroll
            for (int k = 0; k < 3; ++k) {
                int vi = faces[tid * 3 + k];
                float vx = verts[vi * 3 + 0];
                float vy = verts[vi * 3 + 1];
                float vz = verts[vi * 3 + 2];
                float cx = ((r00 * vx + r01 * vy) + r02 * vz) + t0;
                float cy = ((r10 * vx + r11 * vy) + r12 * vz) + t1;
                float cz = ((r20 * vx + r21 * vy) + r22 * vz) + t2;
                X[k] = k00 * cx + k02;
                Y[k] = k11 * cy + k12;
                Z[k] = cz;
            }
            e0dx = X[2]-X[1]; e0dy = Y[2]-Y[1]; e0ax = X[1]; e0ay = Y[1];
            e1dx = X[0]-X[2]; e1dy = Y[0]-Y[2]; e1ax = X[2]; e1ay = Y[2];
            e2dx = X[1]-X[0]; e2dy = Y[1]-Y[0]; e2ax = X[0]; e2ay = Y[0];
            Z0 = Z[0]; Z1 = Z[1]; Z2 = Z[2];

            // bbox vs tile (conservative)
            float minX = fminf(fminf(X[0],X[1]),X[2]);
            float maxX = fmaxf(fmaxf(X[0],X[1]),X[2]);
            float minY = fminf(fminf(Y[0],Y[1]),Y[2]);
            float maxY = fmaxf(fmaxf(Y[0],Y[1]),Y[2]);
            bool bb = (minX <= PX0 + 15.0f + MARG) && (maxX >= PX0 - MARG) &&
                      (minY <= PY0 + 15.0f + MARG) && (maxY >= PY0 - MARG);

            // SAT over the 3 edge-normal axes: triangle's w_e range is
            // [min(0,area),max(0,area)]; tile's w_e range from affine extent.
            float wA0 = e0dx*(PY0-e0ay) - e0dy*(PX0-e0ax);
            float wA1 = e1dx*(PY0-e1ay) - e1dy*(PX0-e1ax);
            float wA2 = e2dx*(PY0-e2ay) - e2dy*(PX0-e2ax);
            float area = (wA0 + wA1) + wA2;
            float amin = fminf(area, 0.0f) - MARG, amax = fmaxf(area, 0.0f) + MARG;

            float s0x = -e0dy*15.0f, s0y = e0dx*15.0f;
            float s1x = -e1dy*15.0f, s1y = e1dx*15.0f;
            float s2x = -e2dy*15.0f, s2y = e2dx*15.0f;
            float t0min = wA0 + fminf(s0x,0.f) + fminf(s0y,0.f);
            float t0max = wA0 + fmaxf(s0x,0.f) + fmaxf(s0y,0.f);
            float t1min = wA1 + fminf(s1x,0.f) + fminf(s1y,0.f);
            float t1max = wA1 + fmaxf(s1x,0.f) + fmaxf(s1y,0.f);
            float t2min = wA2 + fminf(s2x,0.f) + fminf(s2y,0.f);
            float t2max = wA2 + fmaxf(s2x,0.f) + fmaxf(s2y,0.f);
            bool ok0 = (t0max >= amin) && (t0min <= amax);
            bool ok1 = (t1max >= amin) && (t1min <= amax);
            bool ok2 = (t2max >= amin) && (t2min <= amax);
            flag = bb && ok0 && ok1 && ok2;
        }
        mymask = __ballot(flag);
        if ((tid & 63) == 0) smask[tid >> 6] = mymask;
    }
    if (tid == 128) {   // wave 2: hoist light/view normalization
        float lx = light_dir[0], ly = light_dir[1], lz = light_dir[2];
        float ll = sqrtf((lx*lx + ly*ly) + lz*lz) + 1e-8f;
        lx /= ll; ly /= ll; lz /= ll;
        float vx = view_dir[0], vy = view_dir[1], vz = view_dir[2];
        float vl = sqrtf((vx*vx + vy*vy) + vz*vz) + 1e-8f;
        vx /= vl; vy /= vl; vz /= vl;
        float hx = lx + vx, hy = ly + vy, hz = lz + vz;
        float hl = sqrtf((hx*hx + hy*hy) + hz*hz) + 1e-8f;
        slit[0] = lx; slit[1] = ly; slit[2] = lz;
        slit[3] = hx / hl; slit[4] = hy / hl; slit[5] = hz / hl;
    }
    __syncthreads();

    // order-preserving compaction (keeps ascending face index for argmin ties)
    if (flag) {
        int base = (tid >= 64) ? __popcll(smask[0]) : 0;
        int pos  = base + __popcll(mymask & ((1ull << (tid & 63)) - 1ull));
        float* dd = cfd[pos];
        dd[0]=e0dx; dd[1]=e0dy; dd[2]=e0ax; dd[3]=e0ay;
        dd[4]=e1dx; dd[5]=e1dy; dd[6]=e1ax; dd[7]=e1ay;
        dd[8]=e2dx; dd[9]=e2dy; dd[10]=e2ax; dd[11]=e2ay;
        dd[12]=Z0;  dd[13]=Z1;  dd[14]=Z2;  dd[15]=0.0f;
        cid[pos] = tid;
    }
    __syncthreads();
    const int cnt = __popcll(smask[0]) + __popcll(smask[1]);

    // ---------- phase 2: depth/argmin over surviving faces ----------
    const int lx_ = tid & (TILE-1), ly_ = tid / TILE;
    const float px = PX0 + (float)lx_;
    const float py = PY0 + (float)ly_;
    const int p = (ty*TILE + ly_) * RES + (tx*TILE + lx_);

    float best = MAX_DEPTH;
    int winpos = -1;
    for (int i = 0; i < cnt; ++i) {
        const float4 q0 = *reinterpret_cast<const float4*>(&cfd[i][0]);
        const float4 q1 = *reinterpret_cast<const float4*>(&cfd[i][4]);
        const float4 q2 = *reinterpret_cast<const float4*>(&cfd[i][8]);
        const float4 q3 = *reinterpret_cast<const float4*>(&cfd[i][12]);
        float w0 = q0.x * (py - q0.w) - q0.y * (px - q0.z);
        float w1 = q1.x * (py - q1.w) - q1.y * (px - q1.z);
        float w2 = q2.x * (py - q2.w) - q2.y * (px - q2.z);
        float area = (w0 + w1) + w2;
        bool nz = fabsf(area) > EPSF;
        bool inside = (((w0 >= 0.0f) && (w1 >= 0.0f) && (w2 >= 0.0f)) ||
                       ((w0 <= 0.0f) && (w1 <= 0.0f) && (w2 <= 0.0f))) && nz;
        // v_rcp: sign-exact vs IEEE div, ~1e-7 rel -> decisions unchanged
        float inva = __builtin_amdgcn_rcpf(nz ? area : 1.0f);
        float zpix = ((w0 * q3.x + w1 * q3.y) + w2 * q3.z) * inva;
        float zc = (inside && (zpix > 0.0f)) ? zpix : MAX_DEPTH;
        if (zc < best) { best = zc; winpos = i; }   // strict < == first-index tie
    }

    // ---------- phase 3: shade winner ----------
    float r = 0.0f, g = 0.0f, b = 0.0f, mk = 0.0f, depth = MAX_DEPTH;
    if (winpos >= 0) {
        mk = 1.0f;
        depth = best;
        const int f = cid[winpos];
        const float* d = cfd[winpos];
        float u0 = d[0] * (py - d[3])  - d[1] * (px - d[2]);
        float u1 = d[4] * (py - d[7])  - d[5] * (px - d[6]);
        float u2 = d[8] * (py - d[11]) - d[9] * (px - d[10]);
        float ar = (u0 + u1) + u2;
        float inv2 = __builtin_amdgcn_rcpf((fabsf(ar) > EPSF) ? ar : 1.0f);
        float b0 = u0 * inv2, b1 = u1 * inv2, b2 = u2 * inv2;

        const float* nw = normals + f * 9;
        float nx  = (b0 * nw[0] + b1 * nw[3]) + b2 * nw[6];
        float ny  = (b0 * nw[1] + b1 * nw[4]) + b2 * nw[7];
        float nzv = (b0 * nw[2] + b1 * nw[5]) + b2 * nw[8];
        float nl  = __builtin_amdgcn_sqrtf((nx*nx + ny*ny) + nzv*nzv) + 1e-8f;
        float rn  = __builtin_amdgcn_rcpf(nl);
        nx *= rn; ny *= rn; nzv *= rn;

        const float* uvp = uvs + f * 6;
        float uvx = (b0 * uvp[0] + b1 * uvp[2]) + b2 * uvp[4];
        float uvy = (b0 * uvp[1] + b1 * uvp[3]) + b2 * uvp[5];
        float uu = fminf(fmaxf(uvx, 0.0f), 1.0f) * (float)(TEXW - 1);
        float vv = fminf(fmaxf(uvy, 0.0f), 1.0f) * (float)(TEXH - 1);
        int x0 = (int)floorf(uu), y0 = (int)floorf(vv);
        int x1 = min(x0 + 1, TEXW - 1), y1 = min(y0 + 1, TEXH - 1);
        float fx = uu - (float)x0, fy = vv - (float)y0;
        const float* t00 = tex + (y0 * TEXW + x0) * 3;
        const float* t01 = tex + (y0 * TEXW + x1) * 3;
        const float* t10 = tex + (y1 * TEXW + x0) * 3;
        const float* t11 = tex + (y1 * TEXW + x1) * 3;
        float gx = 1.0f - fx, gy = 1.0f - fy;
        float cr = (((t00[0]*gx)*gy + (t01[0]*fx)*gy) + (t10[0]*gx)*fy) + (t11[0]*fx)*fy;
        float cg = (((t00[1]*gx)*gy + (t01[1]*fx)*gy) + (t10[1]*gx)*fy) + (t11[1]*fx)*fy;
        float cb = (((t00[2]*gx)*gy + (t01[2]*fx)*gy) + (t10[2]*gx)*fy) + (t11[2]*fx)*fy;

        float ldx = slit[0], ldy = slit[1], ldz = slit[2];
        float hx  = slit[3], hy  = slit[4], hz  = slit[5];
        float diff = fmaxf((nx*ldx + ny*ldy) + nzv*ldz, 0.0f);
        float sd   = fmaxf((nx*hx  + ny*hy)  + nzv*hz,  0.0f);
        float s2 = sd*sd, s4 = s2*s2, s8 = s4*s4, s16 = s8*s8;   // powf(sd,16)
        float spec  = LIGHT_STREN * s16;
        float scale = AMBIENT + LIGHT_STREN * diff;
        r = cr * scale + spec;
        g = cg * scale + spec;
        b = cb * scale + spec;
    }

    out[p] = depth;
    float* rgb = out + RES * RES;
    rgb[3 * p + 0] = r;
    rgb[3 * p + 1] = g;
    rgb[3 * p + 2] = b;
    out[RES * RES * 4 + p] = mk;
}

extern "C" void kernel_launch(void* const* d_in, const int* in_sizes, int n_in,
                              void* d_out, int out_size, void* d_ws, size_t ws_size,
                              hipStream_t stream) {
    const float* verts     = (const float*)d_in[0];
    const int*   faces     = (const int*)  d_in[1];
    const float* normals   = (const float*)d_in[2];
    const float* uvs       = (const float*)d_in[3];
    const float* tex       = (const float*)d_in[4];
    const float* Ks        = (const float*)d_in[5];
    const float* RTs       = (const float*)d_in[6];
    const float* view_dir  = (const float*)d_in[7];
    const float* light_dir = (const float*)d_in[8];

    int M = in_sizes[1] / 3;
    if (M > MAXF) M = MAXF;                              // dataset M=128
    const int texels = in_sizes[4] / 3;
    const int TEXW = (int)(sqrt((double)texels) + 0.5);
    const int TEXH = TEXW;

    const int blocks = TILESX * TILESX;                  // 1024 tiles
    mesh_render_tiled<<<blocks, 256, 0, stream>>>(
        verts, faces, normals, uvs, tex, Ks, RTs, view_dir, light_dir,
        (float*)d_out, M, TEXW, TEXH);
}

// Round 3
// 15.659 us; speedup vs baseline: 3.5750x; 1.1841x over previous
//
#include <hip/hip_runtime.h>
#include <math.h>

// Strict IEEE f32, no mul+add fusion in the decision path: edge-function sign
// decisions must match the numpy reference bit-for-bit (a flipped hit/miss at
// a silhouette is a depth error of ~98 vs threshold 2.0).
#pragma clang fp contract(off)

#define RES         512
#define TILE        16
#define TILESX      (RES / TILE)
#define MAXF        128
#define MAX_DEPTH   100.0f
#define AMBIENT     0.3f
#define LIGHT_STREN 0.8f
#define EPSF        1e-8f
#define MARG        1.0f    // conservative SAT margin, >> fp rounding at |w|~3e5
#define ZGUARD      1e-3f   // minZ lower-bound guard, >> z interp rounding

__global__ __launch_bounds__(256) void mesh_render_tiled(
    const float* __restrict__ verts,     // (N,3)
    const int*   __restrict__ faces,     // (M,3)
    const float* __restrict__ normals,   // (M,3,3)
    const float* __restrict__ uvs,       // (M,3,2)
    const float* __restrict__ tex,       // (TH,TW,3)
    const float* __restrict__ Ks,        // (3,3)
    const float* __restrict__ RTs,       // (3,4)
    const float* __restrict__ view_dir,  // (3,)
    const float* __restrict__ light_dir, // (3,)
    float* __restrict__ out,             // [depth | rgb | mask]
    int M, int TEXW, int TEXH)
{
    // Compacted per-face data, approximately front-to-back (8 z-buckets):
    // e0{dx,dy,ax,ay} e1{...} e2{...} z0 z1 z2 minZ-guard -> 16 floats
    __shared__ float cfd[MAXF][16];
    __shared__ int   cid[MAXF];
    __shared__ int   scnt[2][8];         // per-wave, per-bucket survivor counts
    __shared__ float slit[6];            // ld(3), h(3) normalized

    const int tid = threadIdx.x;
    const int tx  = blockIdx.x % TILESX;
    const int ty  = blockIdx.x / TILESX;
    const float PX0 = (float)(tx * TILE) + 0.5f;   // first pixel-center x
    const float PY0 = (float)(ty * TILE) + 0.5f;

    // ---------- phase 0+1: transform one face/thread, tile-cull (SAT) ----------
    bool flag = false;
    int  bkt  = -1;
    float e0dx=0,e0dy=0,e0ax=0,e0ay=0, e1dx=0,e1dy=0,e1ax=0,e1ay=0;
    float e2dx=0,e2dy=0,e2ax=0,e2ay=0, Z0=0,Z1=0,Z2=0, MZ=0;
    unsigned long long bmask = 0;

    if (tid < MAXF) {
        if (tid < M) {
            const float r00 = RTs[0], r01 = RTs[1], r02 = RTs[2],  t0 = RTs[3];
            const float r10 = RTs[4], r11 = RTs[5], r12 = RTs[6],  t1 = RTs[7];
            const float r20 = RTs[8], r21 = RTs[9], r22 = RTs[10], t2 = RTs[11];
            const float k00 = Ks[0], k02 = Ks[2], k11 = Ks[4], k12 = Ks[5];
            float X[3], Y[3], Z[3];
            #pragma unroll
            for (int k = 0; k < 3; ++k) {
                int vi = faces[tid * 3 + k];
                float vx = verts[vi * 3 + 0];
                float vy = verts[vi * 3 + 1];
                float vz = verts[vi * 3 + 2];
                float cx = ((r00 * vx + r01 * vy) + r02 * vz) + t0;
                float cy = ((r10 * vx + r11 * vy) + r12 * vz) + t1;
                float cz = ((r20 * vx + r21 * vy) + r22 * vz) + t2;
                X[k] = k00 * cx + k02;
                Y[k] = k11 * cy + k12;
                Z[k] = cz;
            }
            e0dx = X[2]-X[1]; e0dy = Y[2]-Y[1]; e0ax = X[1]; e0ay = Y[1];
            e1dx = X[0]-X[2]; e1dy = Y[0]-Y[2]; e1ax = X[2]; e1ay = Y[2];
            e2dx = X[1]-X[0]; e2dy = Y[1]-Y[0]; e2ax = X[0]; e2ay = Y[0];
            Z0 = Z[0]; Z1 = Z[1]; Z2 = Z[2];
            MZ = fminf(fminf(Z0, Z1), Z2);

            // bbox vs tile (conservative)
            float minX = fminf(fminf(X[0],X[1]),X[2]);
            float maxX = fmaxf(fmaxf(X[0],X[1]),X[2]);
            float minY = fminf(fminf(Y[0],Y[1]),Y[2]);
            float maxY = fmaxf(fmaxf(Y[0],Y[1]),Y[2]);
            bool bb = (minX <= PX0 + 15.0f + MARG) && (maxX >= PX0 - MARG) &&
                      (minY <= PY0 + 15.0f + MARG) && (maxY >= PY0 - MARG);

            // SAT over the 3 edge-normal axes
            float wA0 = e0dx*(PY0-e0ay) - e0dy*(PX0-e0ax);
            float wA1 = e1dx*(PY0-e1ay) - e1dy*(PX0-e1ax);
            float wA2 = e2dx*(PY0-e2ay) - e2dy*(PX0-e2ax);
            float area = (wA0 + wA1) + wA2;
            float amin = fminf(area, 0.0f) - MARG, amax = fmaxf(area, 0.0f) + MARG;

            float s0x = -e0dy*15.0f, s0y = e0dx*15.0f;
            float s1x = -e1dy*15.0f, s1y = e1dx*15.0f;
            float s2x = -e2dy*15.0f, s2y = e2dx*15.0f;
            float t0min = wA0 + fminf(s0x,0.f) + fminf(s0y,0.f);
            float t0max = wA0 + fmaxf(s0x,0.f) + fmaxf(s0y,0.f);
            float t1min = wA1 + fminf(s1x,0.f) + fminf(s1y,0.f);
            float t1max = wA1 + fmaxf(s1x,0.f) + fmaxf(s1y,0.f);
            float t2min = wA2 + fminf(s2x,0.f) + fminf(s2y,0.f);
            float t2max = wA2 + fmaxf(s2x,0.f) + fmaxf(s2y,0.f);
            bool ok0 = (t0max >= amin) && (t0min <= amax);
            bool ok1 = (t1max >= amin) && (t1min <= amax);
            bool ok2 = (t2max >= amin) && (t2min <= amax);
            flag = bb && ok0 && ok1 && ok2;
            if (flag) {
                int bq = (int)((MZ - 1.0f) * 4.0f);      // z in [1,3] -> 8 buckets
                bkt = bq < 0 ? 0 : (bq > 7 ? 7 : bq);
            }
        }
        // per-wave, per-bucket ballots (stable bucket sort keys)
        #pragma unroll
        for (int k = 0; k < 8; ++k) {
            unsigned long long mk = __ballot(flag && (bkt == k));
            if (bkt == k) bmask = mk;
            if ((tid & 63) == 0) scnt[tid >> 6][k] = __popcll(mk);
        }
    }
    if (tid == 128) {   // wave 2: hoist light/view normalization
        float lx = light_dir[0], ly = light_dir[1], lz = light_dir[2];
        float ll = sqrtf((lx*lx + ly*ly) + lz*lz) + 1e-8f;
        lx /= ll; ly /= ll; lz /= ll;
        float vx = view_dir[0], vy = view_dir[1], vz = view_dir[2];
        float vl = sqrtf((vx*vx + vy*vy) + vz*vz) + 1e-8f;
        vx /= vl; vy /= vl; vz /= vl;
        float hx = lx + vx, hy = ly + vy, hz = lz + vz;
        float hl = sqrtf((hx*hx + hy*hy) + hz*hz) + 1e-8f;
        slit[0] = lx; slit[1] = ly; slit[2] = lz;
        slit[3] = hx / hl; slit[4] = hy / hl; slit[5] = hz / hl;
    }
    __syncthreads();

    // bucket-ordered compaction (front-to-back-ish; index-order within bucket)
    if (flag) {
        int wv = tid >> 6;
        int base = 0;
        for (int k = 0; k < bkt; ++k) base += scnt[0][k] + scnt[1][k];
        if (wv == 1) base += scnt[0][bkt];
        int pos = base + __popcll(bmask & ((1ull << (tid & 63)) - 1ull));
        float* dd = cfd[pos];
        dd[0]=e0dx; dd[1]=e0dy; dd[2]=e0ax; dd[3]=e0ay;
        dd[4]=e1dx; dd[5]=e1dy; dd[6]=e1ax; dd[7]=e1ay;
        dd[8]=e2dx; dd[9]=e2dy; dd[10]=e2ax; dd[11]=e2ay;
        dd[12]=Z0;  dd[13]=Z1;  dd[14]=Z2;  dd[15]=MZ - ZGUARD;
        cid[pos] = tid;
    }
    __syncthreads();
    int cnt = 0;
    #pragma unroll
    for (int k = 0; k < 8; ++k) cnt += scnt[0][k] + scnt[1][k];

    // ---------- phase 2: depth/argmin over surviving faces ----------
    const int lx_ = tid & (TILE-1), ly_ = tid / TILE;
    const float px = PX0 + (float)lx_;
    const float py = PY0 + (float)ly_;
    const int p = (ty*TILE + ly_) * RES + (tx*TILE + lx_);

    float best = MAX_DEPTH;
    float w0s = 0.0f, w1s = 0.0f, w2s = 0.0f, invs = 1.0f;
    int winpos = -1;
    for (int i = 0; i < cnt; ++i) {
        const float4 q3 = *reinterpret_cast<const float4*>(&cfd[i][12]);
        // zpix of an inside-pixel is a convex combo of z0..z2 -> bounded below
        // by minZ; guard covers interp rounding. Wave-uniform skip.
        if (__all(q3.w >= best)) continue;
        const float4 q0 = *reinterpret_cast<const float4*>(&cfd[i][0]);
        const float4 q1 = *reinterpret_cast<const float4*>(&cfd[i][4]);
        const float4 q2 = *reinterpret_cast<const float4*>(&cfd[i][8]);
        float w0 = q0.x * (py - q0.w) - q0.y * (px - q0.z);
        float w1 = q1.x * (py - q1.w) - q1.y * (px - q1.z);
        float w2 = q2.x * (py - q2.w) - q2.y * (px - q2.z);
        float area = (w0 + w1) + w2;
        float mn = fminf(fminf(w0, w1), w2);     // v_min3
        float mx = fmaxf(fmaxf(w0, w1), w2);     // v_max3
        bool nz = fabsf(area) > EPSF;
        bool inside = ((mn >= 0.0f) || (mx <= 0.0f)) && nz;
        // v_rcp: sign-exact vs IEEE div, ~1e-7 rel -> decisions unchanged
        float inva = __builtin_amdgcn_rcpf(nz ? area : 1.0f);
        float zpix = ((w0 * q3.x + w1 * q3.y) + w2 * q3.z) * inva;
        float zc = (inside && (zpix > 0.0f)) ? zpix : MAX_DEPTH;
        if (zc < best) {                          // strict < == first-index tie
            best = zc; winpos = i;
            w0s = w0; w1s = w1; w2s = w2; invs = inva;
        }
    }

    // ---------- phase 3: shade winner (no cfd re-reads: w's saved) ----------
    float r = 0.0f, g = 0.0f, b = 0.0f, mk = 0.0f, depth = MAX_DEPTH;
    if (winpos >= 0) {
        mk = 1.0f;
        depth = best;
        const int f = cid[winpos];
        float b0 = w0s * invs, b1 = w1s * invs, b2 = w2s * invs;

        const float* nw = normals + f * 9;
        float nx  = (b0 * nw[0] + b1 * nw[3]) + b2 * nw[6];
        float ny  = (b0 * nw[1] + b1 * nw[4]) + b2 * nw[7];
        float nzv = (b0 * nw[2] + b1 * nw[5]) + b2 * nw[8];
        float nl  = __builtin_amdgcn_sqrtf((nx*nx + ny*ny) + nzv*nzv) + 1e-8f;
        float rn  = __builtin_amdgcn_rcpf(nl);
        nx *= rn; ny *= rn; nzv *= rn;

        const float* uvp = uvs + f * 6;
        float uvx = (b0 * uvp[0] + b1 * uvp[2]) + b2 * uvp[4];
        float uvy = (b0 * uvp[1] + b1 * uvp[3]) + b2 * uvp[5];
        float uu = fminf(fmaxf(uvx, 0.0f), 1.0f) * (float)(TEXW - 1);
        float vv = fminf(fmaxf(uvy, 0.0f), 1.0f) * (float)(TEXH - 1);
        int x0 = (int)floorf(uu), y0 = (int)floorf(vv);
        int x1 = min(x0 + 1, TEXW - 1), y1 = min(y0 + 1, TEXH - 1);
        float fx = uu - (float)x0, fy = vv - (float)y0;
        const float* t00 = tex + (y0 * TEXW + x0) * 3;
        const float* t01 = tex + (y0 * TEXW + x1) * 3;
        const float* t10 = tex + (y1 * TEXW + x0) * 3;
        const float* t11 = tex + (y1 * TEXW + x1) * 3;
        float gx = 1.0f - fx, gy = 1.0f - fy;
        float cr = (((t00[0]*gx)*gy + (t01[0]*fx)*gy) + (t10[0]*gx)*fy) + (t11[0]*fx)*fy;
        float cg = (((t00[1]*gx)*gy + (t01[1]*fx)*gy) + (t10[1]*gx)*fy) + (t11[1]*fx)*fy;
        float cb = (((t00[2]*gx)*gy + (t01[2]*fx)*gy) + (t10[2]*gx)*fy) + (t11[2]*fx)*fy;

        float ldx = slit[0], ldy = slit[1], ldz = slit[2];
        float hx  = slit[3], hy  = slit[4], hz  = slit[5];
        float diff = fmaxf((nx*ldx + ny*ldy) + nzv*ldz, 0.0f);
        float sd   = fmaxf((nx*hx  + ny*hy)  + nzv*hz,  0.0f);
        float s2 = sd*sd, s4 = s2*s2, s8 = s4*s4, s16 = s8*s8;   // powf(sd,16)
        float spec  = LIGHT_STREN * s16;
        float scale = AMBIENT + LIGHT_STREN * diff;
        r = cr * scale + spec;
        g = cg * scale + spec;
        b = cb * scale + spec;
    }

    out[p] = depth;
    float* rgb = out + RES * RES;
    rgb[3 * p + 0] = r;
    rgb[3 * p + 1] = g;
    rgb[3 * p + 2] = b;
    out[RES * RES * 4 + p] = mk;
}

extern "C" void kernel_launch(void* const* d_in, const int* in_sizes, int n_in,
                              void* d_out, int out_size, void* d_ws, size_t ws_size,
                              hipStream_t stream) {
    const float* verts     = (const float*)d_in[0];
    const int*   faces     = (const int*)  d_in[1];
    const float* normals   = (const float*)d_in[2];
    const float* uvs       = (const float*)d_in[3];
    const float* tex       = (const float*)d_in[4];
    const float* Ks        = (const float*)d_in[5];
    const float* RTs       = (const float*)d_in[6];
    const float* view_dir  = (const float*)d_in[7];
    const float* light_dir = (const float*)d_in[8];

    int M = in_sizes[1] / 3;
    if (M > MAXF) M = MAXF;                              // dataset M=128
    const int texels = in_sizes[4] / 3;
    const int TEXW = (int)(sqrt((double)texels) + 0.5);
    const int TEXH = TEXW;

    const int blocks = TILESX * TILESX;                  // 1024 tiles
    mesh_render_tiled<<<blocks, 256, 0, stream>>>(
        verts, faces, normals, uvs, tex, Ks, RTs, view_dir, light_dir,
        (float*)d_out, M, TEXW, TEXH);
}